// Round 1
// baseline (512.986 us; speedup 1.0000x reference)
//
#include <hip/hip_runtime.h>
#include <math.h>

#define TSTEPS 11

__device__ __forceinline__ float skew_el(float v0, float v1, float v2, int i, int j) {
    // skew([v0,v1,v2])[i][j]
    if (i == 0) { if (j == 1) return -v2; if (j == 2) return v1; return 0.f; }
    if (i == 1) { if (j == 0) return v2;  if (j == 2) return -v0; return 0.f; }
    /* i == 2 */ if (j == 0) return -v1; if (j == 1) return v0; return 0.f;
}

__global__ void __launch_bounds__(256)
ekf_kernel(const float* __restrict__ dts,     // (B,11)
           const float* __restrict__ wa,      // (B,12,6)
           const float* __restrict__ Rc,      // (B,12,3,3)
           const float* __restrict__ vel,     // (B,3)
           const float* __restrict__ grav,    // (B,3)
           const float* __restrict__ H0g,     // (B,3,3)
           const float* __restrict__ H1g,     // (B,3,3)
           const float* __restrict__ prot,    // (B,3)
           const float* __restrict__ ptrans,  // (B,3)
           const float* __restrict__ vrot,    // (B,3)
           const float* __restrict__ vtrans,  // (B,3)
           const float* __restrict__ vrstd,   // (B,3)
           const float* __restrict__ vtstd,   // (B,3)
           const float* __restrict__ icds,    // (18,)
           const float* __restrict__ inw,     // (4,1)
           float* __restrict__ out)           // (B,12)
{
    const int b = blockIdx.x;
    const int tid = threadIdx.x;

    __shared__ float P[18][18];
    __shared__ float Phi[18][18];
    __shared__ float Tm[18][18];
    __shared__ float Fm[18][18];
    __shared__ float Ms[18][12];
    __shared__ float PHt[18][6];
    __shared__ float sS[6][7];   // augmented [S | resid]
    __shared__ float qc[12];
    __shared__ float Rs[9];
    __shared__ float wacc[6];    // gyro(3), accel(3)
    __shared__ float yv[6];
    __shared__ float est[12];

    // ---- init: P0 = diag(s^2 + 1e-12), qc = repeat(IMU_NOISE_DIAG,3)*repeat(10^(4 tanh w),3)
    for (int e = tid; e < 324; e += 256) {
        int i = e / 18, j = e % 18;
        float v = 0.f;
        if (i == j) { float s = icds[i]; v = s * s + 1e-12f; }
        P[i][j] = v;
    }
    if (tid < 12) {
        const float IND[4] = {1e-7f, 1e-7f, 0.01f, 0.001f};
        int g = tid / 3;
        qc[tid] = IND[g] * exp10f(4.0f * tanhf(inw[g]));
    }
    __syncthreads();

    const float g0 = grav[b * 3 + 0], g1 = grav[b * 3 + 1], g2 = grav[b * 3 + 2];

    for (int t = 0; t < TSTEPS; ++t) {
        if (tid < 9) Rs[tid] = Rc[(size_t)b * 108 + t * 9 + tid];
        if (tid >= 32 && tid < 38) wacc[tid - 32] = wa[(size_t)b * 72 + t * 6 + (tid - 32)];
        const float dt = dts[b * TSTEPS + t];
        __syncthreads();

        const float w0 = wacc[0], w1 = wacc[1], w2 = wacc[2];
        // Rg = R^T g ; acc2 = Rg + (accel - Rg)   (replicate reference rounding)
        const float Rg0 = Rs[0] * g0 + Rs[3] * g1 + Rs[6] * g2;
        const float Rg1 = Rs[1] * g0 + Rs[4] * g1 + Rs[7] * g2;
        const float Rg2 = Rs[2] * g0 + Rs[5] * g1 + Rs[8] * g2;
        const float a0 = Rg0 + (wacc[3] - Rg0);
        const float a1 = Rg1 + (wacc[4] - Rg1);
        const float a2 = Rg2 + (wacc[5] - Rg2);

        // ---- F (sparse formula, dense store)
        for (int e = tid; e < 324; e += 256) {
            int i = e / 18, j = e % 18;
            float v = 0.f;
            if (i < 3) {
                if (j < 3) v = -skew_el(w0, w1, w2, i, j);
                else if (j >= 12 && j < 15 && (j - 12) == i) v = -1.f;
            } else if (i < 6) {
                if (j >= 6 && j < 9 && (j - 6) == (i - 3)) v = 1.f;
            } else if (i < 9) {
                int r = i - 6;
                if (j < 3) {
                    // -R @ skew(acc2)
                    v = -(Rs[r * 3 + 0] * skew_el(a0, a1, a2, 0, j)
                        + Rs[r * 3 + 1] * skew_el(a0, a1, a2, 1, j)
                        + Rs[r * 3 + 2] * skew_el(a0, a1, a2, 2, j));
                } else if (j >= 9 && j < 12) { if ((j - 9) == r) v = -1.f; }
                else if (j >= 15) v = -Rs[r * 3 + (j - 15)];
            }
            Fm[i][j] = v;
        }
        __syncthreads();

        // ---- Phi = I + F dt + 0.5 F^2 dt^2 ; Phi[0:3,0:3] = exp_SO3(dt*w)^T
        const float hdt2 = 0.5f * dt * dt;
        for (int e = tid; e < 324; e += 256) {
            int i = e / 18, j = e % 18;
            float f2 = 0.f;
            #pragma unroll
            for (int k = 0; k < 9; ++k) f2 += Fm[i][k] * Fm[k][j];  // F rows >=9 are zero
            float v = ((i == j) ? 1.f : 0.f) + dt * Fm[i][j] + hdt2 * f2;
            if (i < 3 && j < 3) {
                float p0 = dt * w0, p1 = dt * w1, p2 = dt * w2;
                float th2 = p0 * p0 + p1 * p1 + p2 * p2;
                float th = sqrtf(th2);
                float A, Bv;
                if (th < 1e-8f) { A = 1.f - th2 / 6.f; Bv = 0.5f - th2 / 24.f; }
                else           { A = sinf(th) / th;    Bv = (1.f - cosf(th)) / th2; }
                // E = I + A K + B K^2 ; Phi[i][j] = E[j][i]
                float K2ji = 0.f;
                #pragma unroll
                for (int k = 0; k < 3; ++k)
                    K2ji += skew_el(p0, p1, p2, j, k) * skew_el(p0, p1, p2, k, i);
                v = ((i == j) ? 1.f : 0.f) + A * skew_el(p0, p1, p2, j, i) + Bv * K2ji;
            }
            Phi[i][j] = v;
        }
        __syncthreads();

        // ---- Tm = Phi @ P ; Ms = Phi @ G (G sparsity folded in)
        for (int e = tid; e < 324; e += 256) {
            int i = e / 18, j = e % 18;
            float s = 0.f;
            #pragma unroll
            for (int k = 0; k < 18; ++k) s += Phi[i][k] * P[k][j];
            Tm[i][j] = s;
        }
        for (int e = tid; e < 216; e += 256) {
            int i = e / 12, k = e % 12;
            float v;
            if (k < 3)      v = -Phi[i][k];
            else if (k < 6) v = Phi[i][12 + (k - 3)];
            else if (k < 9) {
                int c = k - 6;
                v = -(Phi[i][6] * Rs[0 + c] + Phi[i][7] * Rs[3 + c] + Phi[i][8] * Rs[6 + c]);
            }
            else            v = Phi[i][15 + (k - 9)];
            Ms[i][k] = v;
        }
        __syncthreads();

        // ---- P = force_symmetrical(Tm @ Phi^T + (Ms Qc Ms^T) dt)
        //      upper-triangle mirror == compute element (min,max) for both halves
        for (int e = tid; e < 324; e += 256) {
            int i = e / 18, j = e % 18;
            int r = i < j ? i : j;
            int c = i < j ? j : i;
            float s = 0.f;
            #pragma unroll
            for (int k = 0; k < 18; ++k) s += Tm[r][k] * Phi[c][k];
            float q = 0.f;
            #pragma unroll
            for (int k = 0; k < 12; ++k) q += Ms[r][k] * qc[k] * Ms[c][k];
            P[i][j] = s + q * dt;
        }
        __syncthreads();
    }

    // ---- update
    const float* h0 = H0g + (size_t)b * 9;
    const float* h1 = H1g + (size_t)b * 9;

    // PHt[i][m] = sum_k P[i][k] H[m][k]   (H sparse)
    for (int e = tid; e < 108; e += 256) {
        int i = e / 6, m = e % 6;
        float s;
        if (m < 3)
            s = P[i][0] * h0[m * 3] + P[i][1] * h0[m * 3 + 1] + P[i][2] * h0[m * 3 + 2];
        else {
            int r = m - 3;
            s = P[i][0] * h1[r * 3] + P[i][1] * h1[r * 3 + 1] + P[i][2] * h1[r * 3 + 2] + P[i][3 + r];
        }
        PHt[i][m] = s;
    }
    __syncthreads();

    // S = H @ PHt + vis_covar(diag) ; resid in col 6
    if (tid < 36) {
        int m = tid / 6, n = tid % 6;
        float s;
        if (m < 3)
            s = h0[m * 3] * PHt[0][n] + h0[m * 3 + 1] * PHt[1][n] + h0[m * 3 + 2] * PHt[2][n];
        else {
            int r = m - 3;
            s = h1[r * 3] * PHt[0][n] + h1[r * 3 + 1] * PHt[1][n] + h1[r * 3 + 2] * PHt[2][n] + PHt[3 + r][n];
        }
        if (m == n) {
            float sd = (m < 3) ? vrstd[b * 3 + m] : vtstd[b * 3 + m - 3];
            s += (float)(10.0 / (5.4 * 5.4)) * exp10f(3.0f * tanhf(sd));
        }
        sS[m][n] = s;
    }
    if (tid >= 64 && tid < 70) {
        int m = tid - 64;
        sS[m][6] = (m < 3) ? (vrot[b * 3 + m] - prot[b * 3 + m])
                           : (vtrans[b * 3 + m - 3] * 5.4f - ptrans[b * 3 + m - 3]);
    }
    __syncthreads();

    // solve S y = resid  (partial-pivot Gauss-Jordan, single thread)
    if (tid == 0) {
        for (int col = 0; col < 6; ++col) {
            int piv = col; float mx = fabsf(sS[col][col]);
            for (int rr = col + 1; rr < 6; ++rr) {
                float av = fabsf(sS[rr][col]);
                if (av > mx) { mx = av; piv = rr; }
            }
            if (piv != col) {
                for (int cc = 0; cc < 7; ++cc) {
                    float tsw = sS[col][cc]; sS[col][cc] = sS[piv][cc]; sS[piv][cc] = tsw;
                }
            }
            float inv = 1.f / sS[col][col];
            for (int rr = 0; rr < 6; ++rr) {
                if (rr == col) continue;
                float f = sS[rr][col] * inv;
                for (int cc = col; cc < 7; ++cc) sS[rr][cc] -= f * sS[col][cc];
                sS[rr][col] = 0.f;
            }
        }
        for (int m = 0; m < 6; ++m) yv[m] = sS[m][6] / sS[m][m];
    }
    __syncthreads();

    // est = PHt @ y  (only first 12 needed)
    if (tid < 12) {
        float s = 0.f;
        #pragma unroll
        for (int m = 0; m < 6; ++m) s += PHt[tid][m] * yv[m];
        est[tid] = s;
    }
    __syncthreads();

    if (tid < 12) {
        int i = tid;
        float o;
        if (i < 3)
            o = prot[b * 3 + i] + (h0[i * 3] * est[0] + h0[i * 3 + 1] * est[1] + h0[i * 3 + 2] * est[2]);
        else if (i < 6) {
            int r = i - 3;
            o = ptrans[b * 3 + r] + (h1[r * 3] * est[0] + h1[r * 3 + 1] * est[1] + h1[r * 3 + 2] * est[2]) + est[3 + r];
        }
        else if (i < 9) o = vel[b * 3 + (i - 6)] + est[i];
        else            o = grav[b * 3 + (i - 9)] + est[i];
        out[(size_t)b * 12 + i] = o;
    }
}

extern "C" void kernel_launch(void* const* d_in, const int* in_sizes, int n_in,
                              void* d_out, int out_size, void* d_ws, size_t ws_size,
                              hipStream_t stream) {
    const float* dts    = (const float*)d_in[0];
    const float* wa     = (const float*)d_in[1];
    const float* Rc     = (const float*)d_in[2];
    const float* vel    = (const float*)d_in[3];
    const float* grav   = (const float*)d_in[4];
    const float* H0g    = (const float*)d_in[5];
    const float* H1g    = (const float*)d_in[6];
    const float* prot   = (const float*)d_in[7];
    const float* ptrans = (const float*)d_in[8];
    const float* vrot   = (const float*)d_in[9];
    const float* vtrans = (const float*)d_in[10];
    const float* vrstd  = (const float*)d_in[11];
    const float* vtstd  = (const float*)d_in[12];
    const float* icds   = (const float*)d_in[13];
    const float* inw    = (const float*)d_in[14];
    float* outp = (float*)d_out;

    const int B = in_sizes[0] / TSTEPS;
    hipLaunchKernelGGL(ekf_kernel, dim3(B), dim3(256), 0, stream,
                       dts, wa, Rc, vel, grav, H0g, H1g, prot, ptrans,
                       vrot, vtrans, vrstd, vtstd, icds, inw, outp);
}

// Round 2
// 99.765 us; speedup vs baseline: 5.1420x; 5.1420x over previous
//
#include <hip/hip_runtime.h>
#include <math.h>

#define TSTEPS 11
#define PPB 7          // problems per 64-thread block
#define LPP 9          // lanes per problem (one per nonzero S-row)
#define PROB_F 756     // floats of LDS per problem
#define P_OFF 0        // P  [18][20]  (360)
#define S_OFF 360      // S  [9][20]   (180)   (update: PHt [18][8])
#define U_OFF 540      // U  [9][12]   (108)   (update: S6 aug [6][8])
#define M_OFF 648      // M  [9][12]   (108)   (update: y[6], est[12] @ +8)

__device__ __forceinline__ float sk_rc(float v0, float v1, float v2, int i, int j) {
    // skew([v0,v1,v2])[i][j], i runtime, j compile-time ok
    if (i == 0) return (j == 1) ? -v2 : ((j == 2) ?  v1 : 0.f);
    if (i == 1) return (j == 0) ?  v2 : ((j == 2) ? -v0 : 0.f);
    return              (j == 0) ? -v1 : ((j == 1) ?  v0 : 0.f);
}

__global__ void __launch_bounds__(64)
ekf_kernel(const float* __restrict__ dts, const float* __restrict__ wa,
           const float* __restrict__ Rc, const float* __restrict__ vel,
           const float* __restrict__ grav, const float* __restrict__ H0g,
           const float* __restrict__ H1g, const float* __restrict__ prot,
           const float* __restrict__ ptrans, const float* __restrict__ vrot,
           const float* __restrict__ vtrans, const float* __restrict__ vrstd,
           const float* __restrict__ vtstd, const float* __restrict__ icds,
           const float* __restrict__ inw, float* __restrict__ out, int B)
{
    __shared__ __align__(16) float lds[PPB * PROB_F];   // 21168 B
    const int tid = threadIdx.x;
    const int praw = tid / LPP;
    const int r = tid - praw * LPP;            // 0..8
    const int p = (praw < PPB) ? praw : (PPB - 1);
    const int b0 = blockIdx.x * PPB + p;
    const bool valid = (praw < PPB) && (b0 < B);
    const int b = (b0 < B) ? b0 : (B - 1);
    float* L = lds + p * PROB_F;

    // ---- init P0 = diag(icds^2 + 1e-12), pads zeroed
    if (valid) {
        const float4 z = make_float4(0.f, 0.f, 0.f, 0.f);
        float4* r0 = (float4*)&L[P_OFF + r * 20];
        float4* r1 = (float4*)&L[P_OFF + (9 + r) * 20];
#pragma unroll
        for (int q = 0; q < 5; ++q) { r0[q] = z; r1[q] = z; }
        const float d0 = icds[r], d1 = icds[9 + r];
        L[P_OFF + r * 20 + r] = d0 * d0 + 1e-12f;
        L[P_OFF + (9 + r) * 20 + (9 + r)] = d1 * d1 + 1e-12f;
    }

    // ---- process-noise scalars (uniform)
    const float cov0 = exp10f(4.f * tanhf(inw[0]));
    const float cov1 = exp10f(4.f * tanhf(inw[1]));
    const float cov2 = exp10f(4.f * tanhf(inw[2]));
    const float cov3 = exp10f(4.f * tanhf(inw[3]));
    const float qcA = 1e-7f * cov0;   // noise cols 0-2  (gyro)
    const float qcB = 1e-7f * cov1;   // noise cols 3-5  (gyro bias rw)
    const float qcC = 1e-2f * cov2;   // noise cols 6-8  (accel)
    const float qcD = 1e-3f * cov3;   // noise cols 9-11 (accel bias rw)

    const float g0 = grav[(size_t)b * 3 + 0];
    const float g1 = grav[(size_t)b * 3 + 1];
    const float g2 = grav[(size_t)b * 3 + 2];

    __syncthreads();

    float np[18];      // this lane's current P row r (registers)
#pragma unroll
    for (int k = 0; k < 18; ++k) np[k] = 0.f;

    for (int t = 0; t < TSTEPS; ++t) {
        // ---------- phase A ----------
        const float dt = dts[(size_t)b * TSTEPS + t];
        const float hdt2 = 0.5f * dt * dt;
        const size_t rbase = (size_t)b * 108 + (size_t)t * 9;
        const float Rr0 = Rc[rbase + 0], Rr1 = Rc[rbase + 1], Rr2 = Rc[rbase + 2];
        const float Rr3 = Rc[rbase + 3], Rr4 = Rc[rbase + 4], Rr5 = Rc[rbase + 5];
        const float Rr6 = Rc[rbase + 6], Rr7 = Rc[rbase + 7], Rr8 = Rc[rbase + 8];
        const size_t wbase = (size_t)b * 72 + (size_t)t * 6;
        const float w0 = wa[wbase + 0], w1 = wa[wbase + 1], w2 = wa[wbase + 2];
        const float ac0 = wa[wbase + 3], ac1 = wa[wbase + 4], ac2 = wa[wbase + 5];
        // Rg = R^T g ; a' = Rg + (acc - Rg)  (replicate reference rounding)
        const float Rg0 = Rr0 * g0 + Rr3 * g1 + Rr6 * g2;
        const float Rg1 = Rr1 * g0 + Rr4 * g1 + Rr7 * g2;
        const float Rg2 = Rr2 * g0 + Rr5 * g1 + Rr8 * g2;
        const float a0 = Rg0 + (ac0 - Rg0);
        const float a1 = Rg1 + (ac1 - Rg1);
        const float a2 = Rg2 + (ac2 - Rg2);

        // S row r (S = Phi - I, rows 0..8)
        float s[18];
#pragma unroll
        for (int k = 0; k < 18; ++k) s[k] = 0.f;
        if (r < 3) {
            const float p0 = dt * w0, p1 = dt * w1, p2 = dt * w2;
            const float th2 = p0 * p0 + p1 * p1 + p2 * p2;
            const float th = sqrtf(th2);
            float A, Bc;
            if (th < 1e-8f) { A = 1.f - th2 / 6.f; Bc = 0.5f - th2 / 24.f; }
            else            { A = sinf(th) / th;   Bc = (1.f - cosf(th)) / th2; }
            const float prr = (r == 0) ? p0 : ((r == 1) ? p1 : p2);
            // exp^T - I = -A K' + B K'^2 ;  K'^2[i][j] = p_i p_j - d_ij th2
            s[0] = -A * sk_rc(p0, p1, p2, r, 0) + Bc * (prr * p0 - ((r == 0) ? th2 : 0.f));
            s[1] = -A * sk_rc(p0, p1, p2, r, 1) + Bc * (prr * p1 - ((r == 1) ? th2 : 0.f));
            s[2] = -A * sk_rc(p0, p1, p2, r, 2) + Bc * (prr * p2 - ((r == 2) ? th2 : 0.f));
            // Phi[0b][4b] = -dt I + 0.5 dt^2 skew(w)
            s[12] = ((r == 0) ? -dt : 0.f) + hdt2 * sk_rc(w0, w1, w2, r, 0);
            s[13] = ((r == 1) ? -dt : 0.f) + hdt2 * sk_rc(w0, w1, w2, r, 1);
            s[14] = ((r == 2) ? -dt : 0.f) + hdt2 * sk_rc(w0, w1, w2, r, 2);
        } else {
            const int rr = (r < 6) ? (r - 3) : (r - 6);
            const float Ra = Rc[rbase + rr * 3 + 0];
            const float Rb = Rc[rbase + rr * 3 + 1];
            const float Rx = Rc[rbase + rr * 3 + 2];
            // N row = -cross(R_row, a')   (N = -R skew(a'))
            const float n0 = -(Rb * a2 - Rx * a1);
            const float n1 = -(Rx * a0 - Ra * a2);
            const float n2 = -(Ra * a1 - Rb * a0);
            if (r < 6) {
                s[0] = hdt2 * n0; s[1] = hdt2 * n1; s[2] = hdt2 * n2;
                s[6] = (rr == 0) ? dt : 0.f;  s[7] = (rr == 1) ? dt : 0.f;  s[8] = (rr == 2) ? dt : 0.f;
                s[9]  = (rr == 0) ? -hdt2 : 0.f;
                s[10] = (rr == 1) ? -hdt2 : 0.f;
                s[11] = (rr == 2) ? -hdt2 : 0.f;
                s[15] = -hdt2 * Ra; s[16] = -hdt2 * Rb; s[17] = -hdt2 * Rx;
            } else {
                // (N K) row = cross(N_row, w)
                const float k0 = n1 * w2 - n2 * w1;
                const float k1 = n2 * w0 - n0 * w2;
                const float k2 = n0 * w1 - n1 * w0;
                s[0] = dt * n0 - hdt2 * k0; s[1] = dt * n1 - hdt2 * k1; s[2] = dt * n2 - hdt2 * k2;
                s[9]  = (rr == 0) ? -dt : 0.f;
                s[10] = (rr == 1) ? -dt : 0.f;
                s[11] = (rr == 2) ? -dt : 0.f;
                s[12] = -hdt2 * n0; s[13] = -hdt2 * n1; s[14] = -hdt2 * n2;
                s[15] = -dt * Ra; s[16] = -dt * Rb; s[17] = -dt * Rx;
            }
        }

        // preload old P row r + far diag
        float pr[18];
        {
            const float4* prow = (const float4*)&L[P_OFF + r * 20];
            const float4 q0 = prow[0], q1 = prow[1], q2 = prow[2], q3 = prow[3], q4 = prow[4];
            pr[0]=q0.x; pr[1]=q0.y; pr[2]=q0.z; pr[3]=q0.w;
            pr[4]=q1.x; pr[5]=q1.y; pr[6]=q1.z; pr[7]=q1.w;
            pr[8]=q2.x; pr[9]=q2.y; pr[10]=q2.z; pr[11]=q2.w;
            pr[12]=q3.x; pr[13]=q3.y; pr[14]=q3.z; pr[15]=q3.w;
            pr[16]=q4.x; pr[17]=q4.y;
        }
        const float prd = L[P_OFF + (9 + r) * 20 + (9 + r)];

        // U row r = S_row . P  (cols 0..17; pads stay 0)
        float u[20];
#pragma unroll
        for (int k = 0; k < 20; ++k) u[k] = 0.f;
#pragma unroll
        for (int mi = 0; mi < 15; ++mi) {
            const int m = (mi < 3) ? mi : (mi + 3);   // {0,1,2,6..17}: S cols 3-5 are always 0
            const float sv = s[m];
            const float4* pm = (const float4*)&L[P_OFF + m * 20];
            const float4 a0q = pm[0], a1q = pm[1], a2q = pm[2], a3q = pm[3], a4q = pm[4];
            u[0]+=sv*a0q.x; u[1]+=sv*a0q.y; u[2]+=sv*a0q.z; u[3]+=sv*a0q.w;
            u[4]+=sv*a1q.x; u[5]+=sv*a1q.y; u[6]+=sv*a1q.z; u[7]+=sv*a1q.w;
            u[8]+=sv*a2q.x; u[9]+=sv*a2q.y; u[10]+=sv*a2q.z; u[11]+=sv*a2q.w;
            u[12]+=sv*a3q.x; u[13]+=sv*a3q.y; u[14]+=sv*a3q.z; u[15]+=sv*a3q.w;
            u[16]+=sv*a4q.x; u[17]+=sv*a4q.y;
        }

        // M row r = (Phi G) row r
        float Mv[12];
        Mv[0] = -s[0] - ((r == 0) ? 1.f : 0.f);
        Mv[1] = -s[1] - ((r == 1) ? 1.f : 0.f);
        Mv[2] = -s[2] - ((r == 2) ? 1.f : 0.f);
        Mv[3] = s[12]; Mv[4] = s[13]; Mv[5] = s[14];
        {
            const float t0 = s[6] + ((r == 6) ? 1.f : 0.f);
            const float t1 = s[7] + ((r == 7) ? 1.f : 0.f);
            const float t2 = s[8] + ((r == 8) ? 1.f : 0.f);
            Mv[6] = -(t0 * Rr0 + t1 * Rr3 + t2 * Rr6);
            Mv[7] = -(t0 * Rr1 + t1 * Rr4 + t2 * Rr7);
            Mv[8] = -(t0 * Rr2 + t1 * Rr5 + t2 * Rr8);
        }
        Mv[9] = s[15]; Mv[10] = s[16]; Mv[11] = s[17];

        if (valid) {
            float4* sw = (float4*)&L[S_OFF + r * 20];
            sw[0] = make_float4(s[0], s[1], s[2], s[3]);
            sw[1] = make_float4(s[4], s[5], s[6], s[7]);
            sw[2] = make_float4(s[8], s[9], s[10], s[11]);
            sw[3] = make_float4(s[12], s[13], s[14], s[15]);
            sw[4] = make_float4(s[16], s[17], 0.f, 0.f);
            float4* uw = (float4*)&L[U_OFF + r * 12];
            uw[0] = make_float4(u[0], u[1], u[2], u[3]);
            uw[1] = make_float4(u[4], u[5], u[6], u[7]);
            uw[2] = make_float4(u[8], u[9], u[10], u[11]);
            float4* mw = (float4*)&L[M_OFF + r * 12];
            mw[0] = make_float4(Mv[0], Mv[1], Mv[2], Mv[3]);
            mw[1] = make_float4(Mv[4], Mv[5], Mv[6], Mv[7]);
            mw[2] = make_float4(Mv[8], Mv[9], Mv[10], Mv[11]);
        }
        __syncthreads();

        // ---------- phase C ----------
        float mq[12];
        mq[0] = Mv[0] * qcA; mq[1] = Mv[1] * qcA; mq[2] = Mv[2] * qcA;
        mq[3] = Mv[3] * qcB; mq[4] = Mv[4] * qcB; mq[5] = Mv[5] * qcB;
        mq[6] = Mv[6] * qcC; mq[7] = Mv[7] * qcC; mq[8] = Mv[8] * qcC;
        mq[9] = Mv[9] * qcD; mq[10] = Mv[10] * qcD; mq[11] = Mv[11] * qcD;

        float npn[18];
#pragma unroll
        for (int j = 0; j < 9; ++j) {
            const float4* sj = (const float4*)&L[S_OFF + j * 20];
            const float4 s0 = sj[0], s1 = sj[1], s2 = sj[2], s3 = sj[3], s4 = sj[4];
            float vv = u[0]*s0.x + u[1]*s0.y + u[2]*s0.z + u[3]*s0.w
                     + u[4]*s1.x + u[5]*s1.y + u[6]*s1.z + u[7]*s1.w
                     + u[8]*s2.x + u[9]*s2.y + u[10]*s2.z + u[11]*s2.w
                     + u[12]*s3.x + u[13]*s3.y + u[14]*s3.z + u[15]*s3.w
                     + u[16]*s4.x + u[17]*s4.y;
            const float4* mj = (const float4*)&L[M_OFF + j * 12];
            const float4 m0 = mj[0], m1 = mj[1], m2 = mj[2];
            const float qq = mq[0]*m0.x + mq[1]*m0.y + mq[2]*m0.z + mq[3]*m0.w
                           + mq[4]*m1.x + mq[5]*m1.y + mq[6]*m1.z + mq[7]*m1.w
                           + mq[8]*m2.x + mq[9]*m2.y + mq[10]*m2.z + mq[11]*m2.w;
            const float utj = L[U_OFF + j * 12 + r];
            npn[j] = pr[j] + u[j] + utj + vv + dt * qq;
        }
        npn[9]  = pr[9]  + u[9];
        npn[10] = pr[10] + u[10];
        npn[11] = pr[11] + u[11];
        npn[12] = pr[12] + u[12] + dt * mq[3];
        npn[13] = pr[13] + u[13] + dt * mq[4];
        npn[14] = pr[14] + u[14] + dt * mq[5];
        npn[15] = pr[15] + u[15] + dt * mq[9];
        npn[16] = pr[16] + u[16] + dt * mq[10];
        npn[17] = pr[17] + u[17] + dt * mq[11];
        const float ndiag = prd + ((r >= 3) ? dt * ((r < 6) ? qcB : qcD) : 0.f);

        if (valid) {
            float4* pw = (float4*)&L[P_OFF + r * 20];
            pw[0] = make_float4(npn[0], npn[1], npn[2], npn[3]);
            pw[1] = make_float4(npn[4], npn[5], npn[6], npn[7]);
            pw[2] = make_float4(npn[8], npn[9], npn[10], npn[11]);
            pw[3] = make_float4(npn[12], npn[13], npn[14], npn[15]);
            pw[4] = make_float4(npn[16], npn[17], 0.f, 0.f);
#pragma unroll
            for (int j = 9; j < 18; ++j) L[P_OFF + j * 20 + r] = npn[j];  // mirror col
            L[P_OFF + (9 + r) * 20 + (9 + r)] = ndiag;
        }
        __syncthreads();
#pragma unroll
        for (int k = 0; k < 18; ++k) np[k] = npn[k];
    }

    // ---------- update ----------
    float h0v[9], h1v[9];
#pragma unroll
    for (int i = 0; i < 9; ++i) {
        h0v[i] = H0g[(size_t)b * 9 + i];
        h1v[i] = H1g[(size_t)b * 9 + i];
    }
    float pb[6];
    {
        const float4* p9 = (const float4*)&L[P_OFF + (9 + r) * 20];
        const float4 a0q = p9[0], a1q = p9[1];
        pb[0]=a0q.x; pb[1]=a0q.y; pb[2]=a0q.z; pb[3]=a0q.w; pb[4]=a1q.x; pb[5]=a1q.y;
    }
    float phtA[6], phtB[6];
#pragma unroll
    for (int m = 0; m < 3; ++m) {
        phtA[m] = np[0]*h0v[m*3] + np[1]*h0v[m*3+1] + np[2]*h0v[m*3+2];
        phtB[m] = pb[0]*h0v[m*3] + pb[1]*h0v[m*3+1] + pb[2]*h0v[m*3+2];
    }
#pragma unroll
    for (int m = 3; m < 6; ++m) {
        phtA[m] = np[0]*h1v[(m-3)*3] + np[1]*h1v[(m-3)*3+1] + np[2]*h1v[(m-3)*3+2] + np[m];
        phtB[m] = pb[0]*h1v[(m-3)*3] + pb[1]*h1v[(m-3)*3+1] + pb[2]*h1v[(m-3)*3+2] + pb[m];
    }
    if (valid) {
#pragma unroll
        for (int m = 0; m < 6; ++m) {
            L[S_OFF + r * 8 + m] = phtA[m];           // PHt row r
            L[S_OFF + (9 + r) * 8 + m] = phtB[m];     // PHt row 9+r
        }
    }
    __syncthreads();

    if (valid && r < 6) {
        const float* hp = (r < 3) ? (H0g + (size_t)b * 9 + r * 3)
                                  : (H1g + (size_t)b * 9 + (r - 3) * 3);
        const float hr0 = hp[0], hr1 = hp[1], hr2 = hp[2];
        const float VIG = (float)(10.0 / (5.4 * 5.4));
#pragma unroll
        for (int n = 0; n < 6; ++n) {
            float v = hr0 * L[S_OFF + 0 * 8 + n] + hr1 * L[S_OFF + 1 * 8 + n]
                    + hr2 * L[S_OFF + 2 * 8 + n];
            if (r >= 3) v += L[S_OFF + r * 8 + n];
            if (n == r) {
                const float sd = (r < 3) ? vrstd[(size_t)b * 3 + r]
                                         : vtstd[(size_t)b * 3 + (r - 3)];
                v += VIG * exp10f(3.f * tanhf(sd));
            }
            L[U_OFF + r * 8 + n] = v;
        }
        const float rs = (r < 3) ? (vrot[(size_t)b * 3 + r] - prot[(size_t)b * 3 + r])
                                 : (vtrans[(size_t)b * 3 + (r - 3)] * 5.4f - ptrans[(size_t)b * 3 + (r - 3)]);
        L[U_OFF + r * 8 + 6] = rs;
    }
    __syncthreads();

    if (valid && r == 0) {   // 6x6 solve, one lane per problem (7 in parallel per wave)
        float* Sb = &L[U_OFF];
        for (int col = 0; col < 6; ++col) {
            int piv = col; float mx = fabsf(Sb[col * 8 + col]);
            for (int rr2 = col + 1; rr2 < 6; ++rr2) {
                const float av = fabsf(Sb[rr2 * 8 + col]);
                if (av > mx) { mx = av; piv = rr2; }
            }
            if (piv != col) {
                for (int cc = 0; cc <= 6; ++cc) {
                    const float tw = Sb[col * 8 + cc];
                    Sb[col * 8 + cc] = Sb[piv * 8 + cc];
                    Sb[piv * 8 + cc] = tw;
                }
            }
            const float inv = 1.f / Sb[col * 8 + col];
            for (int rr2 = 0; rr2 < 6; ++rr2) {
                if (rr2 == col) continue;
                const float f = Sb[rr2 * 8 + col] * inv;
                for (int cc = col; cc <= 6; ++cc) Sb[rr2 * 8 + cc] -= f * Sb[col * 8 + cc];
            }
        }
#pragma unroll
        for (int m = 0; m < 6; ++m) L[M_OFF + m] = Sb[m * 8 + 6] / Sb[m * 8 + m];
    }
    __syncthreads();

    float ym[6];
#pragma unroll
    for (int m = 0; m < 6; ++m) ym[m] = L[M_OFF + m];
    float estr = 0.f, est9 = 0.f;
#pragma unroll
    for (int m = 0; m < 6; ++m) { estr += phtA[m] * ym[m]; est9 += phtB[m] * ym[m]; }
    if (valid) {
        L[M_OFF + 8 + r] = estr;
        if (r < 3) L[M_OFF + 8 + 9 + r] = est9;
    }
    __syncthreads();

    const float e0 = L[M_OFF + 8 + 0], e1 = L[M_OFF + 8 + 1], e2 = L[M_OFF + 8 + 2];
    if (valid) {
        float o;
        if (r < 3) {
            const float* hq = H0g + (size_t)b * 9 + r * 3;
            o = prot[(size_t)b * 3 + r] + hq[0] * e0 + hq[1] * e1 + hq[2] * e2;
        } else if (r < 6) {
            const int c = r - 3;
            const float* hq = H1g + (size_t)b * 9 + c * 3;
            o = ptrans[(size_t)b * 3 + c] + hq[0] * e0 + hq[1] * e1 + hq[2] * e2 + estr;
        } else {
            o = vel[(size_t)b * 3 + (r - 6)] + estr;
        }
        out[(size_t)b * 12 + r] = o;
        if (r < 3) out[(size_t)b * 12 + 9 + r] = grav[(size_t)b * 3 + r] + est9;
    }
}

extern "C" void kernel_launch(void* const* d_in, const int* in_sizes, int n_in,
                              void* d_out, int out_size, void* d_ws, size_t ws_size,
                              hipStream_t stream) {
    const float* dts    = (const float*)d_in[0];
    const float* wa     = (const float*)d_in[1];
    const float* Rc     = (const float*)d_in[2];
    const float* vel    = (const float*)d_in[3];
    const float* grav   = (const float*)d_in[4];
    const float* H0g    = (const float*)d_in[5];
    const float* H1g    = (const float*)d_in[6];
    const float* prot   = (const float*)d_in[7];
    const float* ptrans = (const float*)d_in[8];
    const float* vrot   = (const float*)d_in[9];
    const float* vtrans = (const float*)d_in[10];
    const float* vrstd  = (const float*)d_in[11];
    const float* vtstd  = (const float*)d_in[12];
    const float* icds   = (const float*)d_in[13];
    const float* inw    = (const float*)d_in[14];
    float* outp = (float*)d_out;

    const int B = in_sizes[0] / TSTEPS;
    const int grid = (B + PPB - 1) / PPB;
    hipLaunchKernelGGL(ekf_kernel, dim3(grid), dim3(64), 0, stream,
                       dts, wa, Rc, vel, grav, H0g, H1g, prot, ptrans,
                       vrot, vtrans, vrstd, vtstd, icds, inw, outp, B);
}

// Round 3
// 43.056 us; speedup vs baseline: 11.9145x; 2.3171x over previous
//
#include <hip/hip_runtime.h>
#include <math.h>

#define TSTEPS 11
#define PPB 7          // problems per 64-thread block
#define LPP 9          // lanes per problem
#define STRIDE 228     // floats of LDS per problem slot (228 % 32 = 4 -> staggered banks)
// main loop: U[9][20] at 0..179
// update:    PHT [18][8] at 0, S6 [6][8] at 144, Y at 192, EST at 200
#define PHT_OFF 0
#define S6_OFF 144
#define Y_OFF 192
#define EST_OFF 200

__device__ __forceinline__ float sel3(int c, float a, float b, float d) {
    float t = (c == 1) ? b : a;
    return (c == 2) ? d : t;
}

__global__ void __launch_bounds__(64)
ekf_kernel(const float* __restrict__ dts, const float* __restrict__ wa,
           const float* __restrict__ Rc, const float* __restrict__ vel,
           const float* __restrict__ grav, const float* __restrict__ H0g,
           const float* __restrict__ H1g, const float* __restrict__ prot,
           const float* __restrict__ ptrans, const float* __restrict__ vrot,
           const float* __restrict__ vtrans, const float* __restrict__ vrstd,
           const float* __restrict__ vtstd, const float* __restrict__ icds,
           const float* __restrict__ inw, float* __restrict__ out, int B)
{
    __shared__ __align__(16) float lds[PPB * STRIDE];   // 6384 B
    const int tid = threadIdx.x;
    const int praw = tid / LPP;
    const int r = tid - praw * LPP;            // 0..8
    const int p = (praw < PPB) ? praw : (PPB - 1);
    const int b0 = blockIdx.x * PPB + p;
    const bool valid = (praw < PPB) && (b0 < B);
    const int b = (b0 < B) ? b0 : (B - 1);
    float* L = lds + p * STRIDE;

    const float qcA = 1e-7f * exp10f(4.f * tanhf(inw[0]));
    const float qcB = 1e-7f * exp10f(4.f * tanhf(inw[1]));
    const float qcC = 1e-2f * exp10f(4.f * tanhf(inw[2]));
    const float qcD = 1e-3f * exp10f(4.f * tanhf(inw[3]));

    const float g0 = grav[(size_t)b*3+0], g1 = grav[(size_t)b*3+1], g2 = grav[(size_t)b*3+2];

    // P columns r and 9+r live in registers for the whole scan
    float np[18], npb[18];
#pragma unroll
    for (int k = 0; k < 18; ++k) { np[k] = 0.f; npb[k] = 0.f; }
    { const float d0 = icds[r];     np[r]      = d0*d0 + 1e-12f;
      const float d1 = icds[9 + r]; npb[9 + r] = d1*d1 + 1e-12f; }

    // current-step inputs (prefetched)
    float dt, Rm[9], w0, w1, w2, ar0, ar1, ar2;
    {
        dt = dts[(size_t)b * TSTEPS];
        const size_t rb = (size_t)b * 108;
#pragma unroll
        for (int i = 0; i < 9; ++i) Rm[i] = Rc[rb + i];
        const float2* wp = (const float2*)(wa + (size_t)b * 72);
        const float2 wq0 = wp[0], wq1 = wp[1], wq2 = wp[2];
        w0 = wq0.x; w1 = wq0.y; w2 = wq1.x; ar0 = wq1.y; ar1 = wq2.x; ar2 = wq2.y;
    }

    for (int t = 0; t < TSTEPS; ++t) {
        // ---- prefetch t+1 inputs (latency hides under this step's compute)
        float dtn = 0.f, Rn[9], wn0 = 0.f, wn1 = 0.f, wn2 = 0.f, an0 = 0.f, an1 = 0.f, an2 = 0.f;
#pragma unroll
        for (int i = 0; i < 9; ++i) Rn[i] = 0.f;
        if (t + 1 < TSTEPS) {
            dtn = dts[(size_t)b * TSTEPS + t + 1];
            const size_t rb = (size_t)b * 108 + (size_t)(t + 1) * 9;
#pragma unroll
            for (int i = 0; i < 9; ++i) Rn[i] = Rc[rb + i];
            const float2* wp = (const float2*)(wa + (size_t)b * 72 + (size_t)(t + 1) * 6);
            const float2 wq0 = wp[0], wq1 = wp[1], wq2 = wp[2];
            wn0 = wq0.x; wn1 = wq0.y; wn2 = wq1.x; an0 = wq1.y; an1 = wq2.x; an2 = wq2.y;
        }

        const float hdt2 = 0.5f * dt * dt;
        // a' = Rg + (acc - Rg)  (replicate reference rounding)
        const float Rg0 = Rm[0]*g0 + Rm[3]*g1 + Rm[6]*g2;
        const float Rg1 = Rm[1]*g0 + Rm[4]*g1 + Rm[7]*g2;
        const float Rg2 = Rm[2]*g0 + Rm[5]*g1 + Rm[8]*g2;
        const float a0 = Rg0 + (ar0 - Rg0);
        const float a1 = Rg1 + (ar1 - Rg1);
        const float a2 = Rg2 + (ar2 - Rg2);

        // ---- S parameters (per-lane full rebuild; all-register)
        // E' = exp_SO3(dt*w)^T - I = -A*Kp + Bc*Kp^2,  Kp = skew(dt*w)
        const float p0 = dt*w0, p1 = dt*w1, p2 = dt*w2;
        const float th2 = p0*p0 + p1*p1 + p2*p2;
        const float th = sqrtf(th2);
        float A, Bc;
        if (th < 1e-8f) { A = 1.f - th2/6.f; Bc = 0.5f - th2/24.f; }
        else            { A = sinf(th)/th;   Bc = (1.f - cosf(th))/th2; }
        float E[9];
        E[0] =  Bc*(p0*p0 - th2);  E[1] =  A*p2 + Bc*p0*p1;  E[2] = -A*p1 + Bc*p0*p2;
        E[3] = -A*p2 + Bc*p1*p0;   E[4] =  Bc*(p1*p1 - th2); E[5] =  A*p0 + Bc*p1*p2;
        E[6] =  A*p1 + Bc*p2*p0;   E[7] = -A*p0 + Bc*p2*p1;  E[8] =  Bc*(p2*p2 - th2);
        // N = -R*skew(a'):  row c = -cross(R_row_c, a')
        float N[9];
        N[0] = -(Rm[1]*a2 - Rm[2]*a1);  N[1] = -(Rm[2]*a0 - Rm[0]*a2);  N[2] = -(Rm[0]*a1 - Rm[1]*a0);
        N[3] = -(Rm[4]*a2 - Rm[5]*a1);  N[4] = -(Rm[5]*a0 - Rm[3]*a2);  N[5] = -(Rm[3]*a1 - Rm[4]*a0);
        N[6] = -(Rm[7]*a2 - Rm[8]*a1);  N[7] = -(Rm[8]*a0 - Rm[6]*a2);  N[8] = -(Rm[6]*a1 - Rm[7]*a0);
        // M2 = dt*N - hdt2*(N*Kw):  (N*Kw) row c = cross(n_c, w)
        float M2[9];
#pragma unroll
        for (int c = 0; c < 3; ++c) {
            const float n0 = N[c*3], n1 = N[c*3+1], n2 = N[c*3+2];
            M2[c*3+0] = dt*n0 - hdt2*(n1*w2 - n2*w1);
            M2[c*3+1] = dt*n1 - hdt2*(n2*w0 - n0*w2);
            M2[c*3+2] = dt*n2 - hdt2*(n0*w1 - n1*w0);
        }

        // S * v (18-vec) -> 9-vec, block-sparse
        auto Smv = [&](const float v[18], float o[9]) {
            const float ev0 = E[0]*v[0] + E[1]*v[1] + E[2]*v[2];
            const float ev1 = E[3]*v[0] + E[4]*v[1] + E[5]*v[2];
            const float ev2 = E[6]*v[0] + E[7]*v[1] + E[8]*v[2];
            const float cx0 = w1*v[14] - w2*v[13];
            const float cx1 = w2*v[12] - w0*v[14];
            const float cx2 = w0*v[13] - w1*v[12];
            o[0] = ev0 - dt*v[12] + hdt2*cx0;
            o[1] = ev1 - dt*v[13] + hdt2*cx1;
            o[2] = ev2 - dt*v[14] + hdt2*cx2;
            const float nv0 = N[0]*v[0] + N[1]*v[1] + N[2]*v[2];
            const float nv1 = N[3]*v[0] + N[4]*v[1] + N[5]*v[2];
            const float nv2 = N[6]*v[0] + N[7]*v[1] + N[8]*v[2];
            const float rv0 = Rm[0]*v[15] + Rm[1]*v[16] + Rm[2]*v[17];
            const float rv1 = Rm[3]*v[15] + Rm[4]*v[16] + Rm[5]*v[17];
            const float rv2 = Rm[6]*v[15] + Rm[7]*v[16] + Rm[8]*v[17];
            o[3] = hdt2*nv0 + dt*v[6] - hdt2*v[9]  - hdt2*rv0;
            o[4] = hdt2*nv1 + dt*v[7] - hdt2*v[10] - hdt2*rv1;
            o[5] = hdt2*nv2 + dt*v[8] - hdt2*v[11] - hdt2*rv2;
            const float mv0 = M2[0]*v[0] + M2[1]*v[1] + M2[2]*v[2];
            const float mv1 = M2[3]*v[0] + M2[4]*v[1] + M2[5]*v[2];
            const float mv2 = M2[6]*v[0] + M2[7]*v[1] + M2[8]*v[2];
            const float nw0 = N[0]*v[12] + N[1]*v[13] + N[2]*v[14];
            const float nw1 = N[3]*v[12] + N[4]*v[13] + N[5]*v[14];
            const float nw2 = N[6]*v[12] + N[7]*v[13] + N[8]*v[14];
            o[6] = mv0 - dt*v[9]  - hdt2*nw0 - dt*rv0;
            o[7] = mv1 - dt*v[10] - hdt2*nw1 - dt*rv1;
            o[8] = mv2 - dt*v[11] - hdt2*nw2 - dt*rv2;
        };

        // ---- phase A: U columns r and 9+r (pure register), exchange via LDS
        float uca[9], ucb[9];
        Smv(np, uca);
        Smv(npb, ucb);
#pragma unroll
        for (int i = 0; i < 9; ++i) {
            L[i*20 + r]     = uca[i];
            L[i*20 + 9 + r] = ucb[i];
        }
        __syncthreads();

        // ---- phase B: read U row r; everything else local
        float ur[18];
        {
            const float4* up = (const float4*)&L[r*20];
            const float4 q0 = up[0], q1 = up[1], q2 = up[2], q3 = up[3];
            const float2 q4 = *(const float2*)&L[r*20 + 16];
            ur[0]=q0.x; ur[1]=q0.y; ur[2]=q0.z; ur[3]=q0.w;
            ur[4]=q1.x; ur[5]=q1.y; ur[6]=q1.z; ur[7]=q1.w;
            ur[8]=q2.x; ur[9]=q2.y; ur[10]=q2.z; ur[11]=q2.w;
            ur[12]=q3.x; ur[13]=q3.y; ur[14]=q3.z; ur[15]=q3.w;
            ur[16]=q4.x; ur[17]=q4.y;
        }

        // m_r = M row r (3-way band)
        float mr[12];
#pragma unroll
        for (int k = 0; k < 12; ++k) mr[k] = 0.f;
        if (r < 3) {
            mr[0] = -(((r==0)?1.f:0.f) + sel3(r, E[0], E[3], E[6]));
            mr[1] = -(((r==1)?1.f:0.f) + sel3(r, E[1], E[4], E[7]));
            mr[2] = -(((r==2)?1.f:0.f) + sel3(r, E[2], E[5], E[8]));
            mr[3] = ((r==0)?-dt:0.f) + hdt2*sel3(r, 0.f,  w2, -w1);
            mr[4] = ((r==1)?-dt:0.f) + hdt2*sel3(r, -w2, 0.f,  w0);
            mr[5] = ((r==2)?-dt:0.f) + hdt2*sel3(r,  w1, -w0, 0.f);
        } else if (r < 6) {
            const int c = r - 3;
            mr[0] = -hdt2*sel3(c, N[0], N[3], N[6]);
            mr[1] = -hdt2*sel3(c, N[1], N[4], N[7]);
            mr[2] = -hdt2*sel3(c, N[2], N[5], N[8]);
            mr[3] = (c==0)?-hdt2:0.f; mr[4] = (c==1)?-hdt2:0.f; mr[5] = (c==2)?-hdt2:0.f;
            const float q0 = sel3(c, Rm[0], Rm[3], Rm[6]);
            const float q1 = sel3(c, Rm[1], Rm[4], Rm[7]);
            const float q2 = sel3(c, Rm[2], Rm[5], Rm[8]);
            mr[6] = -dt*q0;   mr[7] = -dt*q1;   mr[8] = -dt*q2;
            mr[9] = -hdt2*q0; mr[10] = -hdt2*q1; mr[11] = -hdt2*q2;
        } else {
            const int c = r - 6;
            mr[0] = -sel3(c, M2[0], M2[3], M2[6]);
            mr[1] = -sel3(c, M2[1], M2[4], M2[7]);
            mr[2] = -sel3(c, M2[2], M2[5], M2[8]);
            mr[3] = -hdt2*sel3(c, N[0], N[3], N[6]);
            mr[4] = -hdt2*sel3(c, N[1], N[4], N[7]);
            mr[5] = -hdt2*sel3(c, N[2], N[5], N[8]);
            const float q0 = sel3(c, Rm[0], Rm[3], Rm[6]);
            const float q1 = sel3(c, Rm[1], Rm[4], Rm[7]);
            const float q2 = sel3(c, Rm[2], Rm[5], Rm[8]);
            mr[6] = -q0;    mr[7] = -q1;    mr[8] = -q2;
            mr[9] = -dt*q0; mr[10] = -dt*q1; mr[11] = -dt*q2;
        }
        float z[12];
        z[0]=mr[0]*qcA; z[1]=mr[1]*qcA; z[2]=mr[2]*qcA;
        z[3]=mr[3]*qcB; z[4]=mr[4]*qcB; z[5]=mr[5]*qcB;
        z[6]=mr[6]*qcC; z[7]=mr[7]*qcC; z[8]=mr[8]*qcC;
        z[9]=mr[9]*qcD; z[10]=mr[10]*qcD; z[11]=mr[11]*qcD;

        // Q column r, rows 0..8:  Q = M z  (block form)
        float Qc9[9];
        {
            const float ez0 = E[0]*z[0]+E[1]*z[1]+E[2]*z[2];
            const float ez1 = E[3]*z[0]+E[4]*z[1]+E[5]*z[2];
            const float ez2 = E[6]*z[0]+E[7]*z[1]+E[8]*z[2];
            const float cz0 = w1*z[5]-w2*z[4];
            const float cz1 = w2*z[3]-w0*z[5];
            const float cz2 = w0*z[4]-w1*z[3];
            Qc9[0] = -(z[0]+ez0) - dt*z[3] + hdt2*cz0;
            Qc9[1] = -(z[1]+ez1) - dt*z[4] + hdt2*cz1;
            Qc9[2] = -(z[2]+ez2) - dt*z[5] + hdt2*cz2;
            const float nz0 = N[0]*z[0]+N[1]*z[1]+N[2]*z[2];
            const float nz1 = N[3]*z[0]+N[4]*z[1]+N[5]*z[2];
            const float nz2 = N[6]*z[0]+N[7]*z[1]+N[8]*z[2];
            const float rz0 = Rm[0]*z[6]+Rm[1]*z[7]+Rm[2]*z[8];
            const float rz1 = Rm[3]*z[6]+Rm[4]*z[7]+Rm[5]*z[8];
            const float rz2 = Rm[6]*z[6]+Rm[7]*z[7]+Rm[8]*z[8];
            const float sz0 = Rm[0]*z[9]+Rm[1]*z[10]+Rm[2]*z[11];
            const float sz1 = Rm[3]*z[9]+Rm[4]*z[10]+Rm[5]*z[11];
            const float sz2 = Rm[6]*z[9]+Rm[7]*z[10]+Rm[8]*z[11];
            Qc9[3] = -hdt2*nz0 - hdt2*z[3] - dt*rz0 - hdt2*sz0;
            Qc9[4] = -hdt2*nz1 - hdt2*z[4] - dt*rz1 - hdt2*sz1;
            Qc9[5] = -hdt2*nz2 - hdt2*z[5] - dt*rz2 - hdt2*sz2;
            const float mz0 = M2[0]*z[0]+M2[1]*z[1]+M2[2]*z[2];
            const float mz1 = M2[3]*z[0]+M2[4]*z[1]+M2[5]*z[2];
            const float mz2 = M2[6]*z[0]+M2[7]*z[1]+M2[8]*z[2];
            const float nu0 = N[0]*z[3]+N[1]*z[4]+N[2]*z[5];
            const float nu1 = N[3]*z[3]+N[4]*z[4]+N[5]*z[5];
            const float nu2 = N[6]*z[3]+N[7]*z[4]+N[8]*z[5];
            Qc9[6] = -mz0 - hdt2*nu0 - rz0 - dt*sz0;
            Qc9[7] = -mz1 - hdt2*nu1 - rz1 - dt*sz1;
            Qc9[8] = -mz2 - hdt2*nu2 - rz2 - dt*sz2;
        }

        // (U S^T)[:,r] = S * (U row r)^T  (USᵀ symmetric)
        float w9[9];
        Smv(ur, w9);

        // ---- assemble new P columns
#pragma unroll
        for (int i = 0; i < 9; ++i)
            np[i] = np[i] + uca[i] + ur[i] + w9[i] + dt*Qc9[i];
        np[9]  += ur[9];              np[10] += ur[10];             np[11] += ur[11];
        np[12] += ur[12] + dt*z[3];   np[13] += ur[13] + dt*z[4];   np[14] += ur[14] + dt*z[5];
        np[15] += ur[15] + dt*z[9];   np[16] += ur[16] + dt*z[10];  np[17] += ur[17] + dt*z[11];

#pragma unroll
        for (int i = 0; i < 9; ++i) npb[i] += ucb[i];
        if (r >= 3 && r < 6) {               // far column 12+c: += dt*qcB * M[:,3+c]
            const int c = r - 3;
            const float f = dt * qcB;
            const float kc0 = sel3(c, 0.f, -w2,  w1);   // Kw[:,c] = w x e_c
            const float kc1 = sel3(c,  w2, 0.f, -w0);
            const float kc2 = sel3(c, -w1,  w0, 0.f);
            npb[0] += f * (((c==0)?-dt:0.f) + hdt2*kc0);
            npb[1] += f * (((c==1)?-dt:0.f) + hdt2*kc1);
            npb[2] += f * (((c==2)?-dt:0.f) + hdt2*kc2);
            npb[3] += (c==0) ? -f*hdt2 : 0.f;
            npb[4] += (c==1) ? -f*hdt2 : 0.f;
            npb[5] += (c==2) ? -f*hdt2 : 0.f;
            npb[6] += -f*hdt2*sel3(c, N[0], N[1], N[2]);
            npb[7] += -f*hdt2*sel3(c, N[3], N[4], N[5]);
            npb[8] += -f*hdt2*sel3(c, N[6], N[7], N[8]);
        } else if (r >= 6) {                 // far column 15+c: += dt*qcD * M[:,9+c]
            const int c = r - 6;
            const float f = dt * qcD;
            const float rc0 = sel3(c, Rm[0], Rm[1], Rm[2]);
            const float rc1 = sel3(c, Rm[3], Rm[4], Rm[5]);
            const float rc2 = sel3(c, Rm[6], Rm[7], Rm[8]);
            npb[3] += -f*hdt2*rc0;  npb[4] += -f*hdt2*rc1;  npb[5] += -f*hdt2*rc2;
            npb[6] += -f*dt*rc0;    npb[7] += -f*dt*rc1;    npb[8] += -f*dt*rc2;
        }
        npb[12] += (r==3) ? dt*qcB : 0.f;
        npb[13] += (r==4) ? dt*qcB : 0.f;
        npb[14] += (r==5) ? dt*qcB : 0.f;
        npb[15] += (r==6) ? dt*qcD : 0.f;
        npb[16] += (r==7) ? dt*qcD : 0.f;
        npb[17] += (r==8) ? dt*qcD : 0.f;

        __syncthreads();

        // advance prefetched inputs
        dt = dtn;
#pragma unroll
        for (int i = 0; i < 9; ++i) Rm[i] = Rn[i];
        w0 = wn0; w1 = wn1; w2 = wn2; ar0 = an0; ar1 = an1; ar2 = an2;
    }

    // ---------- update ----------
    float h0v[9], h1v[9];
#pragma unroll
    for (int i = 0; i < 9; ++i) { h0v[i] = H0g[(size_t)b*9 + i]; h1v[i] = H1g[(size_t)b*9 + i]; }

    float phtA[6], phtB[6];
#pragma unroll
    for (int m = 0; m < 3; ++m) {
        phtA[m] = np[0]*h0v[m*3] + np[1]*h0v[m*3+1] + np[2]*h0v[m*3+2];
        phtB[m] = npb[0]*h0v[m*3] + npb[1]*h0v[m*3+1] + npb[2]*h0v[m*3+2];
    }
#pragma unroll
    for (int m = 3; m < 6; ++m) {
        phtA[m] = np[0]*h1v[(m-3)*3] + np[1]*h1v[(m-3)*3+1] + np[2]*h1v[(m-3)*3+2] + np[m];
        phtB[m] = npb[0]*h1v[(m-3)*3] + npb[1]*h1v[(m-3)*3+1] + npb[2]*h1v[(m-3)*3+2] + npb[m];
    }
#pragma unroll
    for (int m = 0; m < 6; ++m) {
        L[PHT_OFF + r*8 + m]       = phtA[m];
        L[PHT_OFF + (9 + r)*8 + m] = phtB[m];
    }
    __syncthreads();

    if (valid && r < 6) {
        const float* hp = (r < 3) ? (H0g + (size_t)b*9 + r*3)
                                  : (H1g + (size_t)b*9 + (r-3)*3);
        const float hr0 = hp[0], hr1 = hp[1], hr2 = hp[2];
        const float VIG = (float)(10.0 / (5.4 * 5.4));
#pragma unroll
        for (int n = 0; n < 6; ++n) {
            float v = hr0 * L[PHT_OFF + 0*8 + n] + hr1 * L[PHT_OFF + 1*8 + n]
                    + hr2 * L[PHT_OFF + 2*8 + n];
            if (r >= 3) v += L[PHT_OFF + r*8 + n];
            if (n == r) {
                const float sd = (r < 3) ? vrstd[(size_t)b*3 + r] : vtstd[(size_t)b*3 + (r-3)];
                v += VIG * exp10f(3.f * tanhf(sd));
            }
            L[S6_OFF + r*8 + n] = v;
        }
        const float rs = (r < 3) ? (vrot[(size_t)b*3 + r] - prot[(size_t)b*3 + r])
                                 : (vtrans[(size_t)b*3 + (r-3)] * 5.4f - ptrans[(size_t)b*3 + (r-3)]);
        L[S6_OFF + r*8 + 6] = rs;
    }
    __syncthreads();

    if (valid && r == 0) {   // 6x6 partial-pivot Gauss-Jordan, one lane per problem
        float* Sb = &L[S6_OFF];
        for (int col = 0; col < 6; ++col) {
            int piv = col; float mx = fabsf(Sb[col*8 + col]);
            for (int rr2 = col + 1; rr2 < 6; ++rr2) {
                const float av = fabsf(Sb[rr2*8 + col]);
                if (av > mx) { mx = av; piv = rr2; }
            }
            if (piv != col) {
                for (int cc = 0; cc <= 6; ++cc) {
                    const float tw = Sb[col*8 + cc];
                    Sb[col*8 + cc] = Sb[piv*8 + cc];
                    Sb[piv*8 + cc] = tw;
                }
            }
            const float inv = 1.f / Sb[col*8 + col];
            for (int rr2 = 0; rr2 < 6; ++rr2) {
                if (rr2 == col) continue;
                const float f = Sb[rr2*8 + col] * inv;
                for (int cc = col; cc <= 6; ++cc) Sb[rr2*8 + cc] -= f * Sb[col*8 + cc];
            }
        }
#pragma unroll
        for (int m = 0; m < 6; ++m) L[Y_OFF + m] = Sb[m*8 + 6] / Sb[m*8 + m];
    }
    __syncthreads();

    float ym[6];
#pragma unroll
    for (int m = 0; m < 6; ++m) ym[m] = L[Y_OFF + m];
    float estr = 0.f, est9 = 0.f;
#pragma unroll
    for (int m = 0; m < 6; ++m) { estr += phtA[m]*ym[m]; est9 += phtB[m]*ym[m]; }
    if (valid) {
        L[EST_OFF + r] = estr;
        if (r < 3) L[EST_OFF + 9 + r] = est9;
    }
    __syncthreads();

    const float e0 = L[EST_OFF + 0], e1 = L[EST_OFF + 1], e2 = L[EST_OFF + 2];
    if (valid) {
        float o;
        if (r < 3) {
            const float* hq = H0g + (size_t)b*9 + r*3;
            o = prot[(size_t)b*3 + r] + hq[0]*e0 + hq[1]*e1 + hq[2]*e2;
        } else if (r < 6) {
            const int c = r - 3;
            const float* hq = H1g + (size_t)b*9 + c*3;
            o = ptrans[(size_t)b*3 + c] + hq[0]*e0 + hq[1]*e1 + hq[2]*e2 + estr;
        } else {
            o = vel[(size_t)b*3 + (r-6)] + estr;
        }
        out[(size_t)b*12 + r] = o;
        if (r < 3) out[(size_t)b*12 + 9 + r] = grav[(size_t)b*3 + r] + est9;
    }
}

extern "C" void kernel_launch(void* const* d_in, const int* in_sizes, int n_in,
                              void* d_out, int out_size, void* d_ws, size_t ws_size,
                              hipStream_t stream) {
    const float* dts    = (const float*)d_in[0];
    const float* wa     = (const float*)d_in[1];
    const float* Rc     = (const float*)d_in[2];
    const float* vel    = (const float*)d_in[3];
    const float* grav   = (const float*)d_in[4];
    const float* H0g    = (const float*)d_in[5];
    const float* H1g    = (const float*)d_in[6];
    const float* prot   = (const float*)d_in[7];
    const float* ptrans = (const float*)d_in[8];
    const float* vrot   = (const float*)d_in[9];
    const float* vtrans = (const float*)d_in[10];
    const float* vrstd  = (const float*)d_in[11];
    const float* vtstd  = (const float*)d_in[12];
    const float* icds   = (const float*)d_in[13];
    const float* inw    = (const float*)d_in[14];
    float* outp = (float*)d_out;

    const int B = in_sizes[0] / TSTEPS;
    const int grid = (B + PPB - 1) / PPB;
    hipLaunchKernelGGL(ekf_kernel, dim3(grid), dim3(64), 0, stream,
                       dts, wa, Rc, vel, grav, H0g, H1g, prot, ptrans,
                       vrot, vtrans, vrstd, vtstd, icds, inw, outp, B);
}

// Round 4
// 39.647 us; speedup vs baseline: 12.9390x; 1.0860x over previous
//
#include <hip/hip_runtime.h>
#include <math.h>

#define TSTEPS 11
#define PPB 7          // problems per 64-thread block
#define LPP 9          // lanes per problem
#define STRIDE 228     // floats of LDS per problem slot
// main loop: U[9][20] at 0..179
// update:    PHT [18][8] at 0, S6 [6][8] at 144, Y at 192, EST at 200
#define PHT_OFF 0
#define S6_OFF 144
#define Y_OFF 192
#define EST_OFF 200

__device__ __forceinline__ float sel3(int c, float a, float b, float d) {
    float t = (c == 1) ? b : a;
    return (c == 2) ? d : t;
}

__global__ void __launch_bounds__(64)
ekf_kernel(const float* __restrict__ dts, const float* __restrict__ wa,
           const float* __restrict__ Rc, const float* __restrict__ vel,
           const float* __restrict__ grav, const float* __restrict__ H0g,
           const float* __restrict__ H1g, const float* __restrict__ prot,
           const float* __restrict__ ptrans, const float* __restrict__ vrot,
           const float* __restrict__ vtrans, const float* __restrict__ vrstd,
           const float* __restrict__ vtstd, const float* __restrict__ icds,
           const float* __restrict__ inw, float* __restrict__ out, int B)
{
    __shared__ __align__(16) float lds[PPB * STRIDE];   // 6384 B
    const int tid = threadIdx.x;
    const int praw = tid / LPP;
    const int r = tid - praw * LPP;            // 0..8
    const int p = (praw < PPB) ? praw : (PPB - 1);
    const int b0 = blockIdx.x * PPB + p;
    const bool valid = (praw < PPB) && (b0 < B);
    const int b = (b0 < B) ? b0 : (B - 1);
    float* L = lds + p * STRIDE;

    const float qcA = 1e-7f * exp10f(4.f * tanhf(inw[0]));
    const float qcB = 1e-7f * exp10f(4.f * tanhf(inw[1]));
    const float qcC = 1e-2f * exp10f(4.f * tanhf(inw[2]));
    const float qcD = 1e-3f * exp10f(4.f * tanhf(inw[3]));

    const float g0 = grav[(size_t)b*3+0], g1 = grav[(size_t)b*3+1], g2 = grav[(size_t)b*3+2];

    // P columns r and 9+r live in registers for the whole scan
    float np[18], npb[18];
#pragma unroll
    for (int k = 0; k < 18; ++k) { np[k] = 0.f; npb[k] = 0.f; }
    { const float d0 = icds[r];     np[r]      = d0*d0 + 1e-12f;
      const float d1 = icds[9 + r]; npb[9 + r] = d1*d1 + 1e-12f; }

    // current-step inputs (prefetched)
    float dt, Rm[9], w0, w1, w2, ar0, ar1, ar2;
    {
        dt = dts[(size_t)b * TSTEPS];
        const size_t rb = (size_t)b * 108;
#pragma unroll
        for (int i = 0; i < 9; ++i) Rm[i] = Rc[rb + i];
        const float2* wp = (const float2*)(wa + (size_t)b * 72);
        const float2 wq0 = wp[0], wq1 = wp[1], wq2 = wp[2];
        w0 = wq0.x; w1 = wq0.y; w2 = wq1.x; ar0 = wq1.y; ar1 = wq2.x; ar2 = wq2.y;
    }

    for (int t = 0; t < TSTEPS; ++t) {
        // ---- prefetch t+1 inputs (latency hides under this step's compute)
        float dtn = 0.f, Rn[9], wn0 = 0.f, wn1 = 0.f, wn2 = 0.f, an0 = 0.f, an1 = 0.f, an2 = 0.f;
#pragma unroll
        for (int i = 0; i < 9; ++i) Rn[i] = 0.f;
        if (t + 1 < TSTEPS) {
            dtn = dts[(size_t)b * TSTEPS + t + 1];
            const size_t rb = (size_t)b * 108 + (size_t)(t + 1) * 9;
#pragma unroll
            for (int i = 0; i < 9; ++i) Rn[i] = Rc[rb + i];
            const float2* wp = (const float2*)(wa + (size_t)b * 72 + (size_t)(t + 1) * 6);
            const float2 wq0 = wp[0], wq1 = wp[1], wq2 = wp[2];
            wn0 = wq0.x; wn1 = wq0.y; wn2 = wq1.x; an0 = wq1.y; an1 = wq2.x; an2 = wq2.y;
        }

        const float hdt2 = 0.5f * dt * dt;
        // a' = Rg + (acc - Rg)  (replicate reference rounding)
        const float Rg0 = Rm[0]*g0 + Rm[3]*g1 + Rm[6]*g2;
        const float Rg1 = Rm[1]*g0 + Rm[4]*g1 + Rm[7]*g2;
        const float Rg2 = Rm[2]*g0 + Rm[5]*g1 + Rm[8]*g2;
        const float a0 = Rg0 + (ar0 - Rg0);
        const float a1 = Rg1 + (ar1 - Rg1);
        const float a2 = Rg2 + (ar2 - Rg2);

        // ---- S parameters (per-lane full rebuild; all-register)
        // E' = exp_SO3(dt*w)^T - I = -A*Kp + Bc*Kp^2,  Kp = skew(dt*w)
        // theta = dt*|w| <= ~0.06 -> 3-term Taylor, err ~ th^6/5040 < 1e-10
        const float p0 = dt*w0, p1 = dt*w1, p2 = dt*w2;
        const float th2 = p0*p0 + p1*p1 + p2*p2;
        const float th4 = th2 * th2;
        const float A  = 1.f - th2*(1.f/6.f)  + th4*(1.f/120.f);
        const float Bc = 0.5f - th2*(1.f/24.f) + th4*(1.f/720.f);
        float E[9];
        E[0] =  Bc*(p0*p0 - th2);  E[1] =  A*p2 + Bc*p0*p1;  E[2] = -A*p1 + Bc*p0*p2;
        E[3] = -A*p2 + Bc*p1*p0;   E[4] =  Bc*(p1*p1 - th2); E[5] =  A*p0 + Bc*p1*p2;
        E[6] =  A*p1 + Bc*p2*p0;   E[7] = -A*p0 + Bc*p2*p1;  E[8] =  Bc*(p2*p2 - th2);
        // N = -R*skew(a'):  row c = -cross(R_row_c, a')
        float N[9];
        N[0] = -(Rm[1]*a2 - Rm[2]*a1);  N[1] = -(Rm[2]*a0 - Rm[0]*a2);  N[2] = -(Rm[0]*a1 - Rm[1]*a0);
        N[3] = -(Rm[4]*a2 - Rm[5]*a1);  N[4] = -(Rm[5]*a0 - Rm[3]*a2);  N[5] = -(Rm[3]*a1 - Rm[4]*a0);
        N[6] = -(Rm[7]*a2 - Rm[8]*a1);  N[7] = -(Rm[8]*a0 - Rm[6]*a2);  N[8] = -(Rm[6]*a1 - Rm[7]*a0);
        // M2 = dt*N - hdt2*(N*Kw):  (N*Kw) row c = cross(n_c, w)
        float M2[9];
#pragma unroll
        for (int c = 0; c < 3; ++c) {
            const float n0 = N[c*3], n1 = N[c*3+1], n2 = N[c*3+2];
            M2[c*3+0] = dt*n0 - hdt2*(n1*w2 - n2*w1);
            M2[c*3+1] = dt*n1 - hdt2*(n2*w0 - n0*w2);
            M2[c*3+2] = dt*n2 - hdt2*(n0*w1 - n1*w0);
        }

        // S * v (18-vec) -> 9-vec, block-sparse
        auto Smv = [&](const float v[18], float o[9]) {
            const float ev0 = E[0]*v[0] + E[1]*v[1] + E[2]*v[2];
            const float ev1 = E[3]*v[0] + E[4]*v[1] + E[5]*v[2];
            const float ev2 = E[6]*v[0] + E[7]*v[1] + E[8]*v[2];
            const float cx0 = w1*v[14] - w2*v[13];
            const float cx1 = w2*v[12] - w0*v[14];
            const float cx2 = w0*v[13] - w1*v[12];
            o[0] = ev0 - dt*v[12] + hdt2*cx0;
            o[1] = ev1 - dt*v[13] + hdt2*cx1;
            o[2] = ev2 - dt*v[14] + hdt2*cx2;
            const float nv0 = N[0]*v[0] + N[1]*v[1] + N[2]*v[2];
            const float nv1 = N[3]*v[0] + N[4]*v[1] + N[5]*v[2];
            const float nv2 = N[6]*v[0] + N[7]*v[1] + N[8]*v[2];
            const float rv0 = Rm[0]*v[15] + Rm[1]*v[16] + Rm[2]*v[17];
            const float rv1 = Rm[3]*v[15] + Rm[4]*v[16] + Rm[5]*v[17];
            const float rv2 = Rm[6]*v[15] + Rm[7]*v[16] + Rm[8]*v[17];
            o[3] = hdt2*nv0 + dt*v[6] - hdt2*v[9]  - hdt2*rv0;
            o[4] = hdt2*nv1 + dt*v[7] - hdt2*v[10] - hdt2*rv1;
            o[5] = hdt2*nv2 + dt*v[8] - hdt2*v[11] - hdt2*rv2;
            const float mv0 = M2[0]*v[0] + M2[1]*v[1] + M2[2]*v[2];
            const float mv1 = M2[3]*v[0] + M2[4]*v[1] + M2[5]*v[2];
            const float mv2 = M2[6]*v[0] + M2[7]*v[1] + M2[8]*v[2];
            const float nw0 = N[0]*v[12] + N[1]*v[13] + N[2]*v[14];
            const float nw1 = N[3]*v[12] + N[4]*v[13] + N[5]*v[14];
            const float nw2 = N[6]*v[12] + N[7]*v[13] + N[8]*v[14];
            o[6] = mv0 - dt*v[9]  - hdt2*nw0 - dt*rv0;
            o[7] = mv1 - dt*v[10] - hdt2*nw1 - dt*rv1;
            o[8] = mv2 - dt*v[11] - hdt2*nw2 - dt*rv2;
        };

        // ---- phase A: U columns r and 9+r (pure register), exchange via LDS
        float uca[9], ucb[9];
        Smv(np, uca);
        Smv(npb, ucb);
#pragma unroll
        for (int i = 0; i < 9; ++i) {
            L[i*20 + r]     = uca[i];
            L[i*20 + 9 + r] = ucb[i];
        }
        __syncthreads();

        // ---- phase B: read U row r; everything else local
        float ur[18];
        {
            const float4* up = (const float4*)&L[r*20];
            const float4 q0 = up[0], q1 = up[1], q2 = up[2], q3 = up[3];
            const float2 q4 = *(const float2*)&L[r*20 + 16];
            ur[0]=q0.x; ur[1]=q0.y; ur[2]=q0.z; ur[3]=q0.w;
            ur[4]=q1.x; ur[5]=q1.y; ur[6]=q1.z; ur[7]=q1.w;
            ur[8]=q2.x; ur[9]=q2.y; ur[10]=q2.z; ur[11]=q2.w;
            ur[12]=q3.x; ur[13]=q3.y; ur[14]=q3.z; ur[15]=q3.w;
            ur[16]=q4.x; ur[17]=q4.y;
        }

        // m_r = M row r (3-way band)
        float mr[12];
#pragma unroll
        for (int k = 0; k < 12; ++k) mr[k] = 0.f;
        if (r < 3) {
            mr[0] = -(((r==0)?1.f:0.f) + sel3(r, E[0], E[3], E[6]));
            mr[1] = -(((r==1)?1.f:0.f) + sel3(r, E[1], E[4], E[7]));
            mr[2] = -(((r==2)?1.f:0.f) + sel3(r, E[2], E[5], E[8]));
            mr[3] = ((r==0)?-dt:0.f) + hdt2*sel3(r, 0.f,  w2, -w1);
            mr[4] = ((r==1)?-dt:0.f) + hdt2*sel3(r, -w2, 0.f,  w0);
            mr[5] = ((r==2)?-dt:0.f) + hdt2*sel3(r,  w1, -w0, 0.f);
        } else if (r < 6) {
            const int c = r - 3;
            mr[0] = -hdt2*sel3(c, N[0], N[3], N[6]);
            mr[1] = -hdt2*sel3(c, N[1], N[4], N[7]);
            mr[2] = -hdt2*sel3(c, N[2], N[5], N[8]);
            mr[3] = (c==0)?-hdt2:0.f; mr[4] = (c==1)?-hdt2:0.f; mr[5] = (c==2)?-hdt2:0.f;
            const float q0 = sel3(c, Rm[0], Rm[3], Rm[6]);
            const float q1 = sel3(c, Rm[1], Rm[4], Rm[7]);
            const float q2 = sel3(c, Rm[2], Rm[5], Rm[8]);
            mr[6] = -dt*q0;   mr[7] = -dt*q1;   mr[8] = -dt*q2;
            mr[9] = -hdt2*q0; mr[10] = -hdt2*q1; mr[11] = -hdt2*q2;
        } else {
            const int c = r - 6;
            mr[0] = -sel3(c, M2[0], M2[3], M2[6]);
            mr[1] = -sel3(c, M2[1], M2[4], M2[7]);
            mr[2] = -sel3(c, M2[2], M2[5], M2[8]);
            mr[3] = -hdt2*sel3(c, N[0], N[3], N[6]);
            mr[4] = -hdt2*sel3(c, N[1], N[4], N[7]);
            mr[5] = -hdt2*sel3(c, N[2], N[5], N[8]);
            const float q0 = sel3(c, Rm[0], Rm[3], Rm[6]);
            const float q1 = sel3(c, Rm[1], Rm[4], Rm[7]);
            const float q2 = sel3(c, Rm[2], Rm[5], Rm[8]);
            mr[6] = -q0;    mr[7] = -q1;    mr[8] = -q2;
            mr[9] = -dt*q0; mr[10] = -dt*q1; mr[11] = -dt*q2;
        }
        float z[12];
        z[0]=mr[0]*qcA; z[1]=mr[1]*qcA; z[2]=mr[2]*qcA;
        z[3]=mr[3]*qcB; z[4]=mr[4]*qcB; z[5]=mr[5]*qcB;
        z[6]=mr[6]*qcC; z[7]=mr[7]*qcC; z[8]=mr[8]*qcC;
        z[9]=mr[9]*qcD; z[10]=mr[10]*qcD; z[11]=mr[11]*qcD;

        // Q column r, rows 0..8:  Q = M z  (block form)
        float Qc9[9];
        {
            const float ez0 = E[0]*z[0]+E[1]*z[1]+E[2]*z[2];
            const float ez1 = E[3]*z[0]+E[4]*z[1]+E[5]*z[2];
            const float ez2 = E[6]*z[0]+E[7]*z[1]+E[8]*z[2];
            const float cz0 = w1*z[5]-w2*z[4];
            const float cz1 = w2*z[3]-w0*z[5];
            const float cz2 = w0*z[4]-w1*z[3];
            Qc9[0] = -(z[0]+ez0) - dt*z[3] + hdt2*cz0;
            Qc9[1] = -(z[1]+ez1) - dt*z[4] + hdt2*cz1;
            Qc9[2] = -(z[2]+ez2) - dt*z[5] + hdt2*cz2;
            const float nz0 = N[0]*z[0]+N[1]*z[1]+N[2]*z[2];
            const float nz1 = N[3]*z[0]+N[4]*z[1]+N[5]*z[2];
            const float nz2 = N[6]*z[0]+N[7]*z[1]+N[8]*z[2];
            const float rz0 = Rm[0]*z[6]+Rm[1]*z[7]+Rm[2]*z[8];
            const float rz1 = Rm[3]*z[6]+Rm[4]*z[7]+Rm[5]*z[8];
            const float rz2 = Rm[6]*z[6]+Rm[7]*z[7]+Rm[8]*z[8];
            const float sz0 = Rm[0]*z[9]+Rm[1]*z[10]+Rm[2]*z[11];
            const float sz1 = Rm[3]*z[9]+Rm[4]*z[10]+Rm[5]*z[11];
            const float sz2 = Rm[6]*z[9]+Rm[7]*z[10]+Rm[8]*z[11];
            Qc9[3] = -hdt2*nz0 - hdt2*z[3] - dt*rz0 - hdt2*sz0;
            Qc9[4] = -hdt2*nz1 - hdt2*z[4] - dt*rz1 - hdt2*sz1;
            Qc9[5] = -hdt2*nz2 - hdt2*z[5] - dt*rz2 - hdt2*sz2;
            const float mz0 = M2[0]*z[0]+M2[1]*z[1]+M2[2]*z[2];
            const float mz1 = M2[3]*z[0]+M2[4]*z[1]+M2[5]*z[2];
            const float mz2 = M2[6]*z[0]+M2[7]*z[1]+M2[8]*z[2];
            const float nu0 = N[0]*z[3]+N[1]*z[4]+N[2]*z[5];
            const float nu1 = N[3]*z[3]+N[4]*z[4]+N[5]*z[5];
            const float nu2 = N[6]*z[3]+N[7]*z[4]+N[8]*z[5];
            Qc9[6] = -mz0 - hdt2*nu0 - rz0 - dt*sz0;
            Qc9[7] = -mz1 - hdt2*nu1 - rz1 - dt*sz1;
            Qc9[8] = -mz2 - hdt2*nu2 - rz2 - dt*sz2;
        }

        // (U S^T)[:,r] = S * (U row r)^T  (USᵀ symmetric)
        float w9[9];
        Smv(ur, w9);

        // ---- assemble new P columns
#pragma unroll
        for (int i = 0; i < 9; ++i)
            np[i] = np[i] + uca[i] + ur[i] + w9[i] + dt*Qc9[i];
        np[9]  += ur[9];              np[10] += ur[10];             np[11] += ur[11];
        np[12] += ur[12] + dt*z[3];   np[13] += ur[13] + dt*z[4];   np[14] += ur[14] + dt*z[5];
        np[15] += ur[15] + dt*z[9];   np[16] += ur[16] + dt*z[10];  np[17] += ur[17] + dt*z[11];

#pragma unroll
        for (int i = 0; i < 9; ++i) npb[i] += ucb[i];
        if (r >= 3 && r < 6) {               // far column 12+c: += dt*qcB * M[:,3+c]
            const int c = r - 3;
            const float f = dt * qcB;
            const float kc0 = sel3(c, 0.f, -w2,  w1);   // Kw[:,c] = w x e_c
            const float kc1 = sel3(c,  w2, 0.f, -w0);
            const float kc2 = sel3(c, -w1,  w0, 0.f);
            npb[0] += f * (((c==0)?-dt:0.f) + hdt2*kc0);
            npb[1] += f * (((c==1)?-dt:0.f) + hdt2*kc1);
            npb[2] += f * (((c==2)?-dt:0.f) + hdt2*kc2);
            npb[3] += (c==0) ? -f*hdt2 : 0.f;
            npb[4] += (c==1) ? -f*hdt2 : 0.f;
            npb[5] += (c==2) ? -f*hdt2 : 0.f;
            npb[6] += -f*hdt2*sel3(c, N[0], N[1], N[2]);
            npb[7] += -f*hdt2*sel3(c, N[3], N[4], N[5]);
            npb[8] += -f*hdt2*sel3(c, N[6], N[7], N[8]);
        } else if (r >= 6) {                 // far column 15+c: += dt*qcD * M[:,9+c]
            const int c = r - 6;
            const float f = dt * qcD;
            const float rc0 = sel3(c, Rm[0], Rm[1], Rm[2]);
            const float rc1 = sel3(c, Rm[3], Rm[4], Rm[5]);
            const float rc2 = sel3(c, Rm[6], Rm[7], Rm[8]);
            npb[3] += -f*hdt2*rc0;  npb[4] += -f*hdt2*rc1;  npb[5] += -f*hdt2*rc2;
            npb[6] += -f*dt*rc0;    npb[7] += -f*dt*rc1;    npb[8] += -f*dt*rc2;
        }
        npb[12] += (r==3) ? dt*qcB : 0.f;
        npb[13] += (r==4) ? dt*qcB : 0.f;
        npb[14] += (r==5) ? dt*qcB : 0.f;
        npb[15] += (r==6) ? dt*qcD : 0.f;
        npb[16] += (r==7) ? dt*qcD : 0.f;
        npb[17] += (r==8) ? dt*qcD : 0.f;

        __syncthreads();

        // advance prefetched inputs
        dt = dtn;
#pragma unroll
        for (int i = 0; i < 9; ++i) Rm[i] = Rn[i];
        w0 = wn0; w1 = wn1; w2 = wn2; ar0 = an0; ar1 = an1; ar2 = an2;
    }

    // ---------- update ----------
    float h0v[9], h1v[9];
#pragma unroll
    for (int i = 0; i < 9; ++i) { h0v[i] = H0g[(size_t)b*9 + i]; h1v[i] = H1g[(size_t)b*9 + i]; }

    float phtA[6], phtB[6];
#pragma unroll
    for (int m = 0; m < 3; ++m) {
        phtA[m] = np[0]*h0v[m*3] + np[1]*h0v[m*3+1] + np[2]*h0v[m*3+2];
        phtB[m] = npb[0]*h0v[m*3] + npb[1]*h0v[m*3+1] + npb[2]*h0v[m*3+2];
    }
#pragma unroll
    for (int m = 3; m < 6; ++m) {
        phtA[m] = np[0]*h1v[(m-3)*3] + np[1]*h1v[(m-3)*3+1] + np[2]*h1v[(m-3)*3+2] + np[m];
        phtB[m] = npb[0]*h1v[(m-3)*3] + npb[1]*h1v[(m-3)*3+1] + npb[2]*h1v[(m-3)*3+2] + npb[m];
    }
#pragma unroll
    for (int m = 0; m < 6; ++m) {
        L[PHT_OFF + r*8 + m]       = phtA[m];
        L[PHT_OFF + (9 + r)*8 + m] = phtB[m];
    }
    __syncthreads();

    if (valid && r < 6) {
        const float* hp = (r < 3) ? (H0g + (size_t)b*9 + r*3)
                                  : (H1g + (size_t)b*9 + (r-3)*3);
        const float hr0 = hp[0], hr1 = hp[1], hr2 = hp[2];
        const float VIG = (float)(10.0 / (5.4 * 5.4));
#pragma unroll
        for (int n = 0; n < 6; ++n) {
            float v = hr0 * L[PHT_OFF + 0*8 + n] + hr1 * L[PHT_OFF + 1*8 + n]
                    + hr2 * L[PHT_OFF + 2*8 + n];
            if (r >= 3) v += phtA[n];         // own PHt row r
            if (n == r) {
                const float sd = (r < 3) ? vrstd[(size_t)b*3 + r] : vtstd[(size_t)b*3 + (r-3)];
                v += VIG * exp10f(3.f * tanhf(sd));
            }
            L[S6_OFF + r*8 + n] = v;
        }
        const float rs = (r < 3) ? (vrot[(size_t)b*3 + r] - prot[(size_t)b*3 + r])
                                 : (vtrans[(size_t)b*3 + (r-3)] * 5.4f - ptrans[(size_t)b*3 + (r-3)]);
        L[S6_OFF + r*8 + 6] = rs;
    }
    __syncthreads();

    // 6x6 solve in REGISTERS: lane r==0 of each problem (7 per wave, lockstep,
    // uniform straight-line code, all indices compile-time)
    if (valid && r == 0) {
        float a[6][7];
        const float* Sb = &L[S6_OFF];
#pragma unroll
        for (int m = 0; m < 6; ++m) {
            const float4 q0 = *(const float4*)&Sb[m*8];
            const float4 q1 = *(const float4*)&Sb[m*8 + 4];
            a[m][0]=q0.x; a[m][1]=q0.y; a[m][2]=q0.z; a[m][3]=q0.w;
            a[m][4]=q1.x; a[m][5]=q1.y; a[m][6]=q1.z;
        }
#pragma unroll
        for (int k = 0; k < 6; ++k) {
            // bubble-max partial pivot via conditional swaps
#pragma unroll
            for (int j = k + 1; j < 6; ++j) {
                const bool c = fabsf(a[j][k]) > fabsf(a[k][k]);
#pragma unroll
                for (int cc = k; cc < 7; ++cc) {
                    const float hi = c ? a[j][cc] : a[k][cc];
                    const float lo = c ? a[k][cc] : a[j][cc];
                    a[k][cc] = hi; a[j][cc] = lo;
                }
            }
            const float inv = 1.f / a[k][k];
#pragma unroll
            for (int j = 0; j < 6; ++j) {
                if (j == k) continue;
                const float f = a[j][k] * inv;
#pragma unroll
                for (int cc = k + 1; cc < 7; ++cc) a[j][cc] -= f * a[k][cc];
            }
        }
#pragma unroll
        for (int m = 0; m < 6; ++m) L[Y_OFF + m] = a[m][6] / a[m][m];
    }
    __syncthreads();

    float ym[6];
#pragma unroll
    for (int m = 0; m < 6; ++m) ym[m] = L[Y_OFF + m];
    float estr = 0.f, est9 = 0.f;
#pragma unroll
    for (int m = 0; m < 6; ++m) { estr += phtA[m]*ym[m]; est9 += phtB[m]*ym[m]; }
    if (valid) {
        L[EST_OFF + r] = estr;
        if (r < 3) L[EST_OFF + 9 + r] = est9;
    }
    __syncthreads();

    const float e0 = L[EST_OFF + 0], e1 = L[EST_OFF + 1], e2 = L[EST_OFF + 2];
    if (valid) {
        float o;
        if (r < 3) {
            const float* hq = H0g + (size_t)b*9 + r*3;
            o = prot[(size_t)b*3 + r] + hq[0]*e0 + hq[1]*e1 + hq[2]*e2;
        } else if (r < 6) {
            const int c = r - 3;
            const float* hq = H1g + (size_t)b*9 + c*3;
            o = ptrans[(size_t)b*3 + c] + hq[0]*e0 + hq[1]*e1 + hq[2]*e2 + estr;
        } else {
            o = vel[(size_t)b*3 + (r-6)] + estr;
        }
        out[(size_t)b*12 + r] = o;
        if (r < 3) out[(size_t)b*12 + 9 + r] = grav[(size_t)b*3 + r] + est9;
    }
}

extern "C" void kernel_launch(void* const* d_in, const int* in_sizes, int n_in,
                              void* d_out, int out_size, void* d_ws, size_t ws_size,
                              hipStream_t stream) {
    const float* dts    = (const float*)d_in[0];
    const float* wa     = (const float*)d_in[1];
    const float* Rc     = (const float*)d_in[2];
    const float* vel    = (const float*)d_in[3];
    const float* grav   = (const float*)d_in[4];
    const float* H0g    = (const float*)d_in[5];
    const float* H1g    = (const float*)d_in[6];
    const float* prot   = (const float*)d_in[7];
    const float* ptrans = (const float*)d_in[8];
    const float* vrot   = (const float*)d_in[9];
    const float* vtrans = (const float*)d_in[10];
    const float* vrstd  = (const float*)d_in[11];
    const float* vtstd  = (const float*)d_in[12];
    const float* icds   = (const float*)d_in[13];
    const float* inw    = (const float*)d_in[14];
    float* outp = (float*)d_out;

    const int B = in_sizes[0] / TSTEPS;
    const int grid = (B + PPB - 1) / PPB;
    hipLaunchKernelGGL(ekf_kernel, dim3(grid), dim3(64), 0, stream,
                       dts, wa, Rc, vel, grav, H0g, H1g, prot, ptrans,
                       vrot, vtrans, vrstd, vtstd, icds, inw, outp, B);
}